// Round 6
// baseline (139.901 us; speedup 1.0000x reference)
//
#include <hip/hip_runtime.h>
#include <hip/hip_bf16.h>

#define LL 512
#define HH 128
#define NBATCH 2
#define NT 32

typedef float f32x4 __attribute__((ext_vector_type(4)));
typedef short s16x8 __attribute__((ext_vector_type(8)));
typedef unsigned int u32x4 __attribute__((ext_vector_type(4)));

__device__ __forceinline__ unsigned short f2bfu(float f){
  __hip_bfloat16 h = __float2bfloat16(f);
  return __builtin_bit_cast(unsigned short, h);
}
// max of two packed-bf16 words (both bf16-valued -> exact; max commutes with RN)
__device__ __forceinline__ unsigned int bmax2(unsigned int a, unsigned int b){
  float lo = fmaxf(__uint_as_float(a << 16), __uint_as_float(b << 16));
  float hi = fmaxf(__uint_as_float(a & 0xFFFF0000u), __uint_as_float(b & 0xFFFF0000u));
  return __float_as_uint(hi) | (__float_as_uint(lo) >> 16);
}
__device__ __forceinline__ u32x4 bmax4(u32x4 a, u32x4 b){
  u32x4 r; r[0]=bmax2(a[0],b[0]); r[1]=bmax2(a[1],b[1]);
  r[2]=bmax2(a[2],b[2]); r[3]=bmax2(a[3],b[3]); return r;
}
__device__ __forceinline__ float gelu_f(float v){
  float inner = v * fmaf(0.044715f, v*v, 1.0f);
  float e = __expf(1.5957691216f * inner);
  float s = __fdividef(1.0f, e + 1.0f);
  return fmaf(-v, s, v);
}
__device__ __forceinline__ f32x4 gelu4(f32x4 v){
  f32x4 r;
  #pragma unroll
  for (int i=0;i<4;++i) r[i] = gelu_f(v[i]);
  return r;
}

// ---- prep: t1/t2 (1024 blocks), per-tile pfx/sfx scan tables + tilemax (64), Wcb (8) ----
__global__ void prep_kernel(const float* __restrict__ x, const float* __restrict__ y,
                            const float* __restrict__ W, const float* __restrict__ bias,
                            float* __restrict__ t1, float* __restrict__ t2,
                            float* __restrict__ tilemax, short* __restrict__ pfxT,
                            short* __restrict__ sfxT, short* __restrict__ Wcb){
  int blk = blockIdx.x, tid = threadIdx.x;
  if (blk < NBATCH*LL){
    int b = blk >> 9, l = blk & (LL-1);
    __shared__ float xs[HH], ys[HH];
    size_t base = ((size_t)b*LL + l)*HH;
    if (tid < HH) xs[tid] = x[base + tid];
    else          ys[tid-HH] = y[base + tid - HH];
    __syncthreads();
    int role = tid >> 7, g = tid & (HH-1);
    const float4* wr = (const float4*)(W + (size_t)g*384 + role*HH);
    const float4* vs = (const float4*)(role ? ys : xs);
    float sA = 0.f, sB = 0.f;
    #pragma unroll
    for (int q=0;q<32;q+=2){
      float4 a = vs[q],   w1 = wr[q];
      sA = fmaf(a.x,w1.x, fmaf(a.y,w1.y, fmaf(a.z,w1.z, fmaf(a.w,w1.w, sA))));
      float4 c = vs[q+1], w2 = wr[q+1];
      sB = fmaf(c.x,w2.x, fmaf(c.y,w2.y, fmaf(c.z,w2.z, fmaf(c.w,w2.w, sB))));
    }
    float s = sA + sB;
    if (role == 0) t1[base + g] = s + bias[g];
    else           t2[base + g] = s;
  } else if (blk < NBATCH*LL + NBATCH*NT){
    int e = blk - NBATCH*LL;      // 0..63 -> (b, tile)
    int b = e >> 5, t = e & 31;
    int role = tid >> 7, h = tid & (HH-1);
    const float* xp = x + ((size_t)b*LL + t*16)*HH + h;
    if (role == 0){
      float run = -INFINITY;
      #pragma unroll
      for (int r=0;r<16;++r){ run = fmaxf(run, xp[r*HH]);
        pfxT[(((size_t)b*NT + t)*16 + r)*HH + h] = (short)f2bfu(run); }
      tilemax[((size_t)b*NT + t)*HH + h] = run;
    } else {
      float run = -INFINITY;
      #pragma unroll
      for (int r=15;r>=0;--r){ run = fmaxf(run, xp[r*HH]);
        sfxT[(((size_t)b*NT + t)*16 + r)*HH + h] = (short)f2bfu(run); }
    }
  } else {
    int e0 = ((blk - (NBATCH*LL + NBATCH*NT))*256 + tid)*8;
    #pragma unroll
    for (int i=0;i<8;++i){
      int e = e0 + i; int g = e >> 7, h = e & (HH-1);
      Wcb[e] = (short)f2bfu(W[(size_t)g*384 + 256 + h]);
    }
  }
}

// ---- main: one block per output ROW (b, i); writes one contiguous 256 KB slab ----
__global__ __launch_bounds__(256, 4) void ctx_kernel(
    const float* __restrict__ x, const float* __restrict__ t1,
    const float* __restrict__ t2, const float* __restrict__ tilemax,
    const short* __restrict__ pfxT, const short* __restrict__ sfxT,
    const short* __restrict__ Wcb, float* __restrict__ out)
{
  __shared__ __align__(16) float ownT[16][HH];           // 8 KB (own tile rows, f32)
  __shared__ __align__(16) unsigned short chainU[NT*HH]; // 8 KB (CF for t>ti, CB for t<ti)
  __shared__ __align__(16) unsigned short ownCU[16*HH];  // 4 KB (own-tile ctx, swizzled)

  const int tid = threadIdx.x;
  const int i = blockIdx.x, b = blockIdx.y;
  const int ti = i >> 4, ri = i & 15;
  const size_t bL = (size_t)b*LL;

  { // stage own tile into LDS
    int r = tid >> 4, c0 = (tid & 15)*8;
    const f32x4* sp = (const f32x4*)(x + (bL + ti*16 + r)*HH + c0);
    *(f32x4*)&ownT[r][c0]   = sp[0];
    *(f32x4*)&ownT[r][c0+4] = sp[1];
  }
  __syncthreads();

  { // phase 1: tile-chain scans + own-tile ctx row
    int role = tid >> 7, h = tid & (HH-1);
    const float* tm = tilemax + ((size_t)b*NT)*HH + h;
    if (role == 0){
      float s = -INFINITY;
      for (int r=ri; r<16; ++r) s = fmaxf(s, ownT[r][h]);
      float run = s;                         // CF[t] = max(x[i .. t*16-1])
      for (int t=ti+1; t<NT; ++t){
        chainU[t*HH + h] = f2bfu(run);
        run = fmaxf(run, tm[(size_t)t*HH]);
      }
      float r2 = ownT[ri][h];
      ownCU[ri*HH + (h ^ ((ri&7)<<3))] = f2bfu(r2);
      for (int jr=ri+1; jr<16; ++jr){
        r2 = fmaxf(r2, ownT[jr][h]);
        ownCU[jr*HH + (h ^ ((jr&7)<<3))] = f2bfu(r2);
      }
    } else {
      float p = -INFINITY;
      for (int r=0; r<=ri; ++r) p = fmaxf(p, ownT[r][h]);
      float run = p;                         // CB[t] = max(x[(t+1)*16 .. i])
      for (int t=ti-1; t>=0; --t){
        chainU[t*HH + h] = f2bfu(run);
        run = fmaxf(run, tm[(size_t)t*HH]);
      }
      float r2 = ownT[ri][h];
      for (int jr=ri-1; jr>=0; --jr){
        r2 = fmaxf(r2, ownT[jr][h]);
        ownCU[jr*HH + (h ^ ((jr&7)<<3))] = f2bfu(r2);
      }
    }
  }
  __syncthreads();

  // phase 2: wave w owns j-tiles [8w, 8w+8) -> 64 KB contiguous stores per wave
  const int w = tid >> 6, l = tid & 63, l16 = l & 15, lhi = l >> 4;

  #pragma unroll
  for (int grp=0; grp<2; ++grp){
    const int tbase = w*8 + grp*4;
    u32x4 fr[4][4];
    #pragma unroll
    for (int tt=0; tt<4; ++tt){
      const int t = tbase + tt;
      #pragma unroll
      for (int kb=0; kb<4; ++kb){
        const int h0 = kb*32 + lhi*8;
        u32x4 f;
        if (t == ti){
          f = *(const u32x4*)&ownCU[l16*HH + (h0 ^ ((l16&7)<<3))];
        } else {
          u32x4 c = *(const u32x4*)&chainU[t*HH + h0];   // uniform over l16 (broadcast)
          const short* side = (t > ti) ? pfxT : sfxT;
          u32x4 p = *(const u32x4*)&side[(((size_t)b*NT + t)*16 + l16)*HH + h0];
          f = bmax4(p, c);
        }
        fr[tt][kb] = f;
      }
    }
    #pragma unroll
    for (int nt=0; nt<8; ++nt){
      s16x8 wcf[4];
      #pragma unroll
      for (int kb=0; kb<4; ++kb)
        wcf[kb] = *(const s16x8*)(Wcb + (size_t)(nt*16 + l16)*HH + kb*32 + lhi*8);
      const int gg = nt*16 + lhi*4;
      f32x4 t1v = *(const f32x4*)(t1 + (bL + i)*HH + gg);
      #pragma unroll
      for (int tt=0; tt<4; ++tt){
        f32x4 acc = (f32x4){0.f,0.f,0.f,0.f};
        #pragma unroll
        for (int kb=0; kb<4; ++kb)
          acc = __builtin_amdgcn_mfma_f32_16x16x32_bf16(wcf[kb],
                  __builtin_bit_cast(s16x8, fr[tt][kb]), acc, 0, 0, 0);
        const int j = (tbase + tt)*16 + l16;
        f32x4 t2v = *(const f32x4*)(t2 + (bL + j)*HH + gg);
        *(f32x4*)(out + ((bL + i)*LL + j)*HH + gg) = gelu4(acc + t1v + t2v);
      }
    }
  }
}

extern "C" void kernel_launch(void* const* d_in, const int* in_sizes, int n_in,
                              void* d_out, int out_size, void* d_ws, size_t ws_size,
                              hipStream_t stream) {
  const float* x    = (const float*)d_in[0];
  const float* y    = (const float*)d_in[1];
  const float* W    = (const float*)d_in[2];
  const float* bias = (const float*)d_in[3];
  float* out = (float*)d_out;

  float* t1      = (float*)d_ws;                      // B*L*H f32
  float* t2      = t1 + (size_t)NBATCH*LL*HH;         // B*L*H f32
  float* tilemax = t2 + (size_t)NBATCH*LL*HH;         // B*NT*H f32
  short* Wcb  = (short*)(tilemax + (size_t)NBATCH*NT*HH);  // 128*128 bf16
  short* pfxT = Wcb + (size_t)HH*HH;                  // B*NT*16*H bf16
  short* sfxT = pfxT + (size_t)NBATCH*NT*16*HH;       // B*NT*16*H bf16

  prep_kernel<<<NBATCH*LL + NBATCH*NT + 8, 256, 0, stream>>>(
      x, y, W, bias, t1, t2, tilemax, pfxT, sfxT, Wcb);
  ctx_kernel<<<dim3(LL, NBATCH), 256, 0, stream>>>(
      x, t1, t2, tilemax, pfxT, sfxT, Wcb, out);
}